// Round 2
// baseline (312.954 us; speedup 1.0000x reference)
//
#include <hip/hip_runtime.h>

// Problem constants
constexpr int Bz  = 8;
constexpr int Lz  = 512;
constexpr int Hz  = 256;
constexpr int H2z = 512;
constexpr int Vz  = 32000;
constexpr int Mz  = Bz * Lz;      // 4096 tokens
constexpr float CF = 0.05f;       // 1 - ALPHA

// ---------------------------------------------------------------------------
// GEMM1: y1[4096,512] = relu(embed[seq][4096,256] @ W1[256,512] + b1)
// 64x64 tile, BK=16, 256 threads, 4x4 per thread, fp32. Software-pipelined:
// next tile's global loads issue right after the barrier, before compute.
// ---------------------------------------------------------------------------
__global__ __launch_bounds__(256) void k_gemm1(
    const int* __restrict__ seq, const float* __restrict__ embed,
    const float* __restrict__ W1, const float* __restrict__ b1,
    float* __restrict__ y1)
{
  __shared__ float As[16][68];
  __shared__ float Bs[16][68];
  const int tid = threadIdx.x;
  const int n0 = blockIdx.x * 64, m0 = blockIdx.y * 64;
  const int tx = tid & 15, ty = tid >> 4;
  const int arow = tid >> 2, akq = (tid & 3) << 2;
  const int bk = tid >> 4, bnq = (tid & 15) << 2;
  const long abase = (long)seq[m0 + arow] * Hz;

  float acc[4][4] = {};
  float4 av = *(const float4*)(embed + abase + akq);
  float4 bv = *(const float4*)(W1 + (long)bk * H2z + n0 + bnq);
  for (int k0 = 0; k0 < Hz; k0 += 16) {
    __syncthreads();
    As[akq + 0][arow] = av.x; As[akq + 1][arow] = av.y;
    As[akq + 2][arow] = av.z; As[akq + 3][arow] = av.w;
    *(float4*)&Bs[bk][bnq] = bv;
    __syncthreads();
    if (k0 + 16 < Hz) {
      av = *(const float4*)(embed + abase + k0 + 16 + akq);
      bv = *(const float4*)(W1 + (long)(k0 + 16 + bk) * H2z + n0 + bnq);
    }
#pragma unroll
    for (int kk = 0; kk < 16; ++kk) {
      float a[4], bb[4];
      *(float4*)a  = *(const float4*)&As[kk][ty << 2];
      *(float4*)bb = *(const float4*)&Bs[kk][tx << 2];
#pragma unroll
      for (int i = 0; i < 4; ++i)
#pragma unroll
        for (int j = 0; j < 4; ++j) acc[i][j] = fmaf(a[i], bb[j], acc[i][j]);
    }
  }
  const float4 bias = *(const float4*)(b1 + n0 + (tx << 2));
#pragma unroll
  for (int i = 0; i < 4; ++i) {
    float4 o;
    o.x = fmaxf(acc[i][0] + bias.x, 0.0f);
    o.y = fmaxf(acc[i][1] + bias.y, 0.0f);
    o.z = fmaxf(acc[i][2] + bias.z, 0.0f);
    o.w = fmaxf(acc[i][3] + bias.w, 0.0f);
    *(float4*)(y1 + (long)(m0 + (ty << 2) + i) * H2z + n0 + (tx << 2)) = o;
  }
}

// ---------------------------------------------------------------------------
// GEMM2: x[4096,256] = y1 @ W2[512,256] + b2 + embed[seq]  (residual fused)
// ---------------------------------------------------------------------------
__global__ __launch_bounds__(256) void k_gemm2(
    const int* __restrict__ seq, const float* __restrict__ embed,
    const float* __restrict__ y1, const float* __restrict__ W2,
    const float* __restrict__ b2, float* __restrict__ x)
{
  __shared__ float As[16][68];
  __shared__ float Bs[16][68];
  const int tid = threadIdx.x;
  const int n0 = blockIdx.x * 64, m0 = blockIdx.y * 64;
  const int tx = tid & 15, ty = tid >> 4;
  const int arow = tid >> 2, akq = (tid & 3) << 2;
  const int bk = tid >> 4, bnq = (tid & 15) << 2;
  const long abase = (long)(m0 + arow) * H2z;

  float acc[4][4] = {};
  float4 av = *(const float4*)(y1 + abase + akq);
  float4 bv = *(const float4*)(W2 + (long)bk * Hz + n0 + bnq);
  for (int k0 = 0; k0 < H2z; k0 += 16) {
    __syncthreads();
    As[akq + 0][arow] = av.x; As[akq + 1][arow] = av.y;
    As[akq + 2][arow] = av.z; As[akq + 3][arow] = av.w;
    *(float4*)&Bs[bk][bnq] = bv;
    __syncthreads();
    if (k0 + 16 < H2z) {
      av = *(const float4*)(y1 + abase + k0 + 16 + akq);
      bv = *(const float4*)(W2 + (long)(k0 + 16 + bk) * Hz + n0 + bnq);
    }
#pragma unroll
    for (int kk = 0; kk < 16; ++kk) {
      float a[4], bb[4];
      *(float4*)a  = *(const float4*)&As[kk][ty << 2];
      *(float4*)bb = *(const float4*)&Bs[kk][tx << 2];
#pragma unroll
      for (int i = 0; i < 4; ++i)
#pragma unroll
        for (int j = 0; j < 4; ++j) acc[i][j] = fmaf(a[i], bb[j], acc[i][j]);
    }
  }
  const float4 bias = *(const float4*)(b2 + n0 + (tx << 2));
#pragma unroll
  for (int i = 0; i < 4; ++i) {
    const int row = m0 + (ty << 2) + i;
    const float4 ev = *(const float4*)(embed + (long)seq[row] * Hz + n0 + (tx << 2));
    float4 o;
    o.x = acc[i][0] + bias.x + ev.x;
    o.y = acc[i][1] + bias.y + ev.y;
    o.z = acc[i][2] + bias.z + ev.z;
    o.w = acc[i][3] + bias.w + ev.w;
    *(float4*)(x + (long)row * Hz + n0 + (tx << 2)) = o;
  }
}

// ---------------------------------------------------------------------------
// LayerNorm + L2-normalized copy. One wave per row, 4 elems/lane.
// ---------------------------------------------------------------------------
__global__ __launch_bounds__(256) void k_ln(
    const float* __restrict__ x, const float* __restrict__ gamma,
    const float* __restrict__ beta, float* __restrict__ h,
    float* __restrict__ hn)
{
  const int lane = threadIdx.x & 63;
  const long row = (long)blockIdx.x * 4 + (threadIdx.x >> 6);
  const int off = lane << 2;
  const float4 xv = *(const float4*)(x + row * Hz + off);
  float s  = xv.x + xv.y + xv.z + xv.w;
  float ss = xv.x * xv.x + xv.y * xv.y + xv.z * xv.z + xv.w * xv.w;
#pragma unroll
  for (int o = 32; o >= 1; o >>= 1) { s += __shfl_xor(s, o); ss += __shfl_xor(ss, o); }
  const float mu   = s * (1.0f / Hz);
  const float var  = ss * (1.0f / Hz) - mu * mu;
  const float rstd = rsqrtf(var + 1e-5f);
  const float4 gv = *(const float4*)(gamma + off);
  const float4 bv = *(const float4*)(beta + off);
  float4 hv;
  hv.x = (xv.x - mu) * rstd * gv.x + bv.x;
  hv.y = (xv.y - mu) * rstd * gv.y + bv.y;
  hv.z = (xv.z - mu) * rstd * gv.z + bv.z;
  hv.w = (xv.w - mu) * rstd * gv.w + bv.w;
  *(float4*)(h + row * Hz + off) = hv;
  float hs = hv.x * hv.x + hv.y * hv.y + hv.z * hv.z + hv.w * hv.w;
#pragma unroll
  for (int o = 32; o >= 1; o >>= 1) hs += __shfl_xor(hs, o);
  const float inv = 1.0f / fmaxf(sqrtf(hs), 1e-12f);
  float4 nv = {hv.x * inv, hv.y * inv, hv.z * inv, hv.w * inv};
  *(float4*)(hn + row * Hz + off) = nv;
}

// ---------------------------------------------------------------------------
// Gram matrices for the blocked recurrence. Block bi covers virtual steps
// s = 16*bi + i  ->  t_i = 510 - 16*bi - i  (i = 0..15; t=-1 at bi=31,i=15 is
// a dummy whose d is forced to 0 in k_recur, so garbage values are harmless;
// the t=-1 read lands in the hb region of ws -- mapped memory).
// Layout: G[(b*32+bi)*256 + j*16 + i] = kn_{t_i} . kn_{t_j}
// ---------------------------------------------------------------------------
__global__ __launch_bounds__(256) void k_gram(
    const float* __restrict__ hn, float* __restrict__ G)
{
  __shared__ float rows[16][260];
  const int bi = blockIdx.x, b = blockIdx.y;
  const int tid = threadIdx.x;
  const float* hnb = hn + (long)b * Lz * Hz;
  const int tt0 = 510 - (bi << 4);
  const int r = tid >> 4, ch = (tid & 15) << 4;
  const float* src = hnb + (long)(tt0 - r) * Hz + ch;
  const float4 v0 = *(const float4*)(src + 0);
  const float4 v1 = *(const float4*)(src + 4);
  const float4 v2 = *(const float4*)(src + 8);
  const float4 v3 = *(const float4*)(src + 12);
  *(float4*)&rows[r][ch + 0]  = v0;
  *(float4*)&rows[r][ch + 4]  = v1;
  *(float4*)&rows[r][ch + 8]  = v2;
  *(float4*)&rows[r][ch + 12] = v3;
  __syncthreads();
  const int j = tid >> 4, i = tid & 15;
  float acc = 0.0f;
#pragma unroll 4
  for (int e = 0; e < Hz; e += 4) {
    const float4 a = *(const float4*)&rows[i][e];
    const float4 c = *(const float4*)&rows[j][e];
    acc += a.x * c.x + a.y * c.y + a.z * c.z + a.w * c.w;
  }
  G[((long)b * 32 + bi) * 256 + j * 16 + i] = acc;
}

// ---------------------------------------------------------------------------
// Blocked delta-rule recurrence (backward on vectors, T=16 per block):
//   p = Kn_blk u ; d_i = p_i - c Sum_{j<i} G_ij d_j ;
//   m += c K_blk^T d ; u -= c Kn_blk^T d
// One wave per batch. Fuses r = m @ Wrp + brp.
// ---------------------------------------------------------------------------
__global__ __launch_bounds__(64, 1) void k_recur(
    const float* __restrict__ h, const float* __restrict__ hn,
    const float* __restrict__ G, const float* __restrict__ Wrp,
    const float* __restrict__ brp, float* __restrict__ r)
{
  __shared__ float Gs[256];
  const int b = blockIdx.x, lane = threadIdx.x;
  const float* hb  = h  + (long)b * Lz * Hz;
  const float* hnb = hn + (long)b * Lz * Hz;
  const int off = lane << 2;
  float4 u = *(const float4*)(hb + 511 * Hz + off);
  float4 m = {0.0f, 0.0f, 0.0f, 0.0f};

  for (int bi = 0; bi < 32; ++bi) {
    const int tt0 = 510 - (bi << 4);
    const float4 g4 = *(const float4*)(G + ((long)b * 32 + bi) * 256 + off);
    float4 knb[16], kb[16];
#pragma unroll
    for (int i = 0; i < 16; ++i) {
      const long t = tt0 - i;          // t=-1 at (bi=31,i=15): garbage, d forced 0
      knb[i] = *(const float4*)(hnb + t * Hz + off);
      kb[i]  = *(const float4*)(hb  + t * Hz + off);
    }
    *(float4*)&Gs[off] = g4;
    __syncthreads();
    // p = Kn_blk . u  (batched 16-way allreduce: independent shuffles pipeline)
    float pp[16];
#pragma unroll
    for (int i = 0; i < 16; ++i)
      pp[i] = knb[i].x * u.x + knb[i].y * u.y + knb[i].z * u.z + knb[i].w * u.w;
#pragma unroll
    for (int s = 32; s >= 1; s >>= 1)
#pragma unroll
      for (int i = 0; i < 16; ++i) pp[i] += __shfl_xor(pp[i], s);
    // triangular solve (redundant per-lane; G rows broadcast from LDS)
    float d[16];
#pragma unroll
    for (int i = 0; i < 16; ++i) d[i] = pp[i];
#pragma unroll
    for (int j = 0; j < 15; ++j) {
      const float dj = d[j];
#pragma unroll
      for (int i = j + 1; i < 16; ++i)
        d[i] = fmaf(-CF * Gs[j * 16 + i], dj, d[i]);
    }
    if (tt0 - 15 < 0) d[15] = 0.0f;    // dummy step (only bi=31)
    // rank-16 updates
#pragma unroll
    for (int i = 0; i < 16; ++i) {
      const float cd = CF * d[i];
      m.x = fmaf(cd, kb[i].x, m.x); m.y = fmaf(cd, kb[i].y, m.y);
      m.z = fmaf(cd, kb[i].z, m.z); m.w = fmaf(cd, kb[i].w, m.w);
      u.x = fmaf(-cd, knb[i].x, u.x); u.y = fmaf(-cd, knb[i].y, u.y);
      u.z = fmaf(-cd, knb[i].z, u.z); u.w = fmaf(-cd, knb[i].w, u.w);
    }
    __syncthreads();                   // protect Gs before next block's write
  }
  // r[b] = m @ Wrp + brp
  float racc[4] = {0.0f, 0.0f, 0.0f, 0.0f};
  for (int j = 0; j < 64; ++j) {
    float4 mj;
    mj.x = __shfl(m.x, j); mj.y = __shfl(m.y, j);
    mj.z = __shfl(m.z, j); mj.w = __shfl(m.w, j);
    const float mv[4] = {mj.x, mj.y, mj.z, mj.w};
#pragma unroll
    for (int c = 0; c < 4; ++c) {
      const long i = (long)j * 4 + c;
#pragma unroll
      for (int cc = 0; cc < 4; ++cc)
        racc[cc] = fmaf(mv[c], Wrp[i * Hz + cc * 64 + lane], racc[cc]);
    }
  }
#pragma unroll
  for (int cc = 0; cc < 4; ++cc)
    r[b * Hz + cc * 64 + lane] = racc[cc] + brp[cc * 64 + lane];
}

// ---------------------------------------------------------------------------
// out[8,32000] = r[8,256] @ Wout[256,32000] + bout.
// 500 wgs x 256 thr: 64 cols/wg, 4 i-slices of 64, LDS combine.
// ---------------------------------------------------------------------------
__global__ __launch_bounds__(256) void k_outproj(
    const float* __restrict__ r, const float* __restrict__ Wout,
    const float* __restrict__ bout, float* __restrict__ out)
{
  __shared__ float rs[8 * Hz];          // r, [b][i] flat
  __shared__ float part[4][8][64];
  const int tid = threadIdx.x, w = tid >> 6, lane = tid & 63;
  ((float4*)rs)[tid * 2 + 0] = ((const float4*)r)[tid * 2 + 0];
  ((float4*)rs)[tid * 2 + 1] = ((const float4*)r)[tid * 2 + 1];
  __syncthreads();
  const int col = blockIdx.x * 64 + lane;
  float acc[8] = {};
  const int i0 = w << 6;
#pragma unroll 8
  for (int ii = 0; ii < 64; ++ii) {
    const int i = i0 + ii;
    const float wv = Wout[(long)i * Vz + col];
#pragma unroll
    for (int bb = 0; bb < 8; ++bb) acc[bb] = fmaf(rs[bb * Hz + i], wv, acc[bb]);
  }
#pragma unroll
  for (int bb = 0; bb < 8; ++bb) part[w][bb][lane] = acc[bb];
  __syncthreads();
  const float bo = bout[col];
  float s0 = part[0][w][lane] + part[1][w][lane] + part[2][w][lane] + part[3][w][lane];
  out[(long)w * Vz + col] = s0 + bo;
  const int w4 = w + 4;
  float s1 = part[0][w4][lane] + part[1][w4][lane] + part[2][w4][lane] + part[3][w4][lane];
  out[(long)w4 * Vz + col] = s1 + bo;
}

// ---------------------------------------------------------------------------
extern "C" void kernel_launch(void* const* d_in, const int* in_sizes, int n_in,
                              void* d_out, int out_size, void* d_ws, size_t ws_size,
                              hipStream_t stream)
{
  const int*   seq   = (const int*)  d_in[0];
  const float* embed = (const float*)d_in[1];
  const float* W1    = (const float*)d_in[2];
  const float* b1    = (const float*)d_in[3];
  const float* W2    = (const float*)d_in[4];
  const float* b2    = (const float*)d_in[5];
  const float* gamma = (const float*)d_in[6];
  const float* beta  = (const float*)d_in[7];
  const float* Wrp   = (const float*)d_in[8];
  const float* brp   = (const float*)d_in[9];
  const float* Wout  = (const float*)d_in[10];
  const float* bout  = (const float*)d_in[11];
  float* out = (float*)d_out;

  char* ws = (char*)d_ws;
  float* y1  = (float*)ws;                                    // 8 MB
  float* xb  = (float*)(ws + (size_t)Mz * H2z * 4);           // 4 MB
  float* hb  = (float*)(ws + (size_t)Mz * H2z * 4 + (size_t)Mz * Hz * 4);
  float* hnb = (float*)(ws + (size_t)Mz * H2z * 4 + 2 * (size_t)Mz * Hz * 4);
  float* rb  = (float*)(ws + (size_t)Mz * H2z * 4 + 3 * (size_t)Mz * Hz * 4);
  float* Gb  = (float*)(ws + (size_t)Mz * H2z * 4 + 3 * (size_t)Mz * Hz * 4 + 8192);

  k_gemm1<<<dim3(H2z / 64, Mz / 64), 256, 0, stream>>>(seq, embed, W1, b1, y1);
  k_gemm2<<<dim3(Hz / 64, Mz / 64), 256, 0, stream>>>(seq, embed, y1, W2, b2, xb);
  k_ln<<<Mz / 4, 256, 0, stream>>>(xb, gamma, beta, hb, hnb);
  k_gram<<<dim3(32, 8), 256, 0, stream>>>(hnb, Gb);
  k_recur<<<Bz, 64, 0, stream>>>(hb, hnb, Gb, Wrp, brp, rb);
  k_outproj<<<Vz / 64, 256, 0, stream>>>(rb, Wout, bout, out);
}

// Round 4
// 290.752 us; speedup vs baseline: 1.0764x; 1.0764x over previous
//
#include <hip/hip_runtime.h>

// Problem constants
constexpr int Bz  = 8;
constexpr int Lz  = 512;
constexpr int Hz  = 256;
constexpr int H2z = 512;
constexpr int Vz  = 32000;
constexpr int Mz  = Bz * Lz;      // 4096 tokens
constexpr float CF = 0.05f;       // 1 - ALPHA
constexpr int Tb  = 32;           // recurrence block size
constexpr int NB  = 16;           // blocks: Tb*NB = 512 = 511 real steps + 1 dummy

// ---------------------------------------------------------------------------
// GEMM1: y1[4096,512] = relu(embed[seq][4096,256] @ W1[256,512] + b1)
// ---------------------------------------------------------------------------
__global__ __launch_bounds__(256) void k_gemm1(
    const int* __restrict__ seq, const float* __restrict__ embed,
    const float* __restrict__ W1, const float* __restrict__ b1,
    float* __restrict__ y1)
{
  __shared__ float As[16][68];
  __shared__ float Bs[16][68];
  const int tid = threadIdx.x;
  const int n0 = blockIdx.x * 64, m0 = blockIdx.y * 64;
  const int tx = tid & 15, ty = tid >> 4;
  const int arow = tid >> 2, akq = (tid & 3) << 2;
  const int bk = tid >> 4, bnq = (tid & 15) << 2;
  const long abase = (long)seq[m0 + arow] * Hz;

  float acc[4][4] = {};
  float4 av = *(const float4*)(embed + abase + akq);
  float4 bv = *(const float4*)(W1 + (long)bk * H2z + n0 + bnq);
  for (int k0 = 0; k0 < Hz; k0 += 16) {
    __syncthreads();
    As[akq + 0][arow] = av.x; As[akq + 1][arow] = av.y;
    As[akq + 2][arow] = av.z; As[akq + 3][arow] = av.w;
    *(float4*)&Bs[bk][bnq] = bv;
    __syncthreads();
    if (k0 + 16 < Hz) {
      av = *(const float4*)(embed + abase + k0 + 16 + akq);
      bv = *(const float4*)(W1 + (long)(k0 + 16 + bk) * H2z + n0 + bnq);
    }
#pragma unroll
    for (int kk = 0; kk < 16; ++kk) {
      float a[4], bb[4];
      *(float4*)a  = *(const float4*)&As[kk][ty << 2];
      *(float4*)bb = *(const float4*)&Bs[kk][tx << 2];
#pragma unroll
      for (int i = 0; i < 4; ++i)
#pragma unroll
        for (int j = 0; j < 4; ++j) acc[i][j] = fmaf(a[i], bb[j], acc[i][j]);
    }
  }
  const float4 bias = *(const float4*)(b1 + n0 + (tx << 2));
#pragma unroll
  for (int i = 0; i < 4; ++i) {
    float4 o;
    o.x = fmaxf(acc[i][0] + bias.x, 0.0f);
    o.y = fmaxf(acc[i][1] + bias.y, 0.0f);
    o.z = fmaxf(acc[i][2] + bias.z, 0.0f);
    o.w = fmaxf(acc[i][3] + bias.w, 0.0f);
    *(float4*)(y1 + (long)(m0 + (ty << 2) + i) * H2z + n0 + (tx << 2)) = o;
  }
}

// ---------------------------------------------------------------------------
// GEMM2: x[4096,256] = y1 @ W2[512,256] + b2 + embed[seq]  (residual fused)
// ---------------------------------------------------------------------------
__global__ __launch_bounds__(256) void k_gemm2(
    const int* __restrict__ seq, const float* __restrict__ embed,
    const float* __restrict__ y1, const float* __restrict__ W2,
    const float* __restrict__ b2, float* __restrict__ x)
{
  __shared__ float As[16][68];
  __shared__ float Bs[16][68];
  const int tid = threadIdx.x;
  const int n0 = blockIdx.x * 64, m0 = blockIdx.y * 64;
  const int tx = tid & 15, ty = tid >> 4;
  const int arow = tid >> 2, akq = (tid & 3) << 2;
  const int bk = tid >> 4, bnq = (tid & 15) << 2;
  const long abase = (long)(m0 + arow) * H2z;

  float acc[4][4] = {};
  float4 av = *(const float4*)(y1 + abase + akq);
  float4 bv = *(const float4*)(W2 + (long)bk * Hz + n0 + bnq);
  for (int k0 = 0; k0 < H2z; k0 += 16) {
    __syncthreads();
    As[akq + 0][arow] = av.x; As[akq + 1][arow] = av.y;
    As[akq + 2][arow] = av.z; As[akq + 3][arow] = av.w;
    *(float4*)&Bs[bk][bnq] = bv;
    __syncthreads();
    if (k0 + 16 < H2z) {
      av = *(const float4*)(y1 + abase + k0 + 16 + akq);
      bv = *(const float4*)(W2 + (long)(k0 + 16 + bk) * Hz + n0 + bnq);
    }
#pragma unroll
    for (int kk = 0; kk < 16; ++kk) {
      float a[4], bb[4];
      *(float4*)a  = *(const float4*)&As[kk][ty << 2];
      *(float4*)bb = *(const float4*)&Bs[kk][tx << 2];
#pragma unroll
      for (int i = 0; i < 4; ++i)
#pragma unroll
        for (int j = 0; j < 4; ++j) acc[i][j] = fmaf(a[i], bb[j], acc[i][j]);
    }
  }
  const float4 bias = *(const float4*)(b2 + n0 + (tx << 2));
#pragma unroll
  for (int i = 0; i < 4; ++i) {
    const int row = m0 + (ty << 2) + i;
    const float4 ev = *(const float4*)(embed + (long)seq[row] * Hz + n0 + (tx << 2));
    float4 o;
    o.x = acc[i][0] + bias.x + ev.x;
    o.y = acc[i][1] + bias.y + ev.y;
    o.z = acc[i][2] + bias.z + ev.z;
    o.w = acc[i][3] + bias.w + ev.w;
    *(float4*)(x + (long)row * Hz + n0 + (tx << 2)) = o;
  }
}

// ---------------------------------------------------------------------------
// LayerNorm + L2-normalized copy. One wave per row, 4 elems/lane.
// ---------------------------------------------------------------------------
__global__ __launch_bounds__(256) void k_ln(
    const float* __restrict__ x, const float* __restrict__ gamma,
    const float* __restrict__ beta, float* __restrict__ h,
    float* __restrict__ hn)
{
  const int lane = threadIdx.x & 63;
  const long row = (long)blockIdx.x * 4 + (threadIdx.x >> 6);
  const int off = lane << 2;
  const float4 xv = *(const float4*)(x + row * Hz + off);
  float s  = xv.x + xv.y + xv.z + xv.w;
  float ss = xv.x * xv.x + xv.y * xv.y + xv.z * xv.z + xv.w * xv.w;
#pragma unroll
  for (int o = 32; o >= 1; o >>= 1) { s += __shfl_xor(s, o); ss += __shfl_xor(ss, o); }
  const float mu   = s * (1.0f / Hz);
  const float var  = ss * (1.0f / Hz) - mu * mu;
  const float rstd = rsqrtf(var + 1e-5f);
  const float4 gv = *(const float4*)(gamma + off);
  const float4 bv = *(const float4*)(beta + off);
  float4 hv;
  hv.x = (xv.x - mu) * rstd * gv.x + bv.x;
  hv.y = (xv.y - mu) * rstd * gv.y + bv.y;
  hv.z = (xv.z - mu) * rstd * gv.z + bv.z;
  hv.w = (xv.w - mu) * rstd * gv.w + bv.w;
  *(float4*)(h + row * Hz + off) = hv;
  float hs = hv.x * hv.x + hv.y * hv.y + hv.z * hv.z + hv.w * hv.w;
#pragma unroll
  for (int o = 32; o >= 1; o >>= 1) hs += __shfl_xor(hs, o);
  const float inv = 1.0f / fmaxf(sqrtf(hs), 1e-12f);
  float4 nv = {hv.x * inv, hv.y * inv, hv.z * inv, hv.w * inv};
  *(float4*)(hn + row * Hz + off) = nv;
}

// ---------------------------------------------------------------------------
// Gram + precomputed block-solve inverse. One WG per (block bi, batch b).
// Steps s = Tb*bi + i -> t_i = 510 - Tb*bi - i.  Dummy t=-1 staged as zeros.
// Solves (I + CF*L) W = I,  L[i][j] = G[j][i] (j<i), stores W TRANSPOSED:
//   Wt[(b*NB+bi)*1024 + k*32 + j] = W[j][k]   so d_j = sum_k Wt[k][j] p_k.
// ---------------------------------------------------------------------------
__global__ __launch_bounds__(256) void k_gramw(
    const float* __restrict__ hn, float* __restrict__ Wt)
{
  __shared__ float rows[32][260];
  __shared__ float Gs[32][33];
  const int bi = blockIdx.x, b = blockIdx.y;
  const int tid = threadIdx.x;
  const float* hnb = hn + (long)b * Lz * Hz;
  const int t0 = 510 - bi * Tb;
  {  // stage 32 kn rows (zero the dummy)
    const int r = tid >> 3, off = (tid & 7) * 32;
    const int t = t0 - r;
    if (t >= 0) {
      const float* src = hnb + (long)t * Hz + off;
#pragma unroll
      for (int q = 0; q < 8; ++q)
        *(float4*)&rows[r][off + 4 * q] = *(const float4*)(src + 4 * q);
    } else {
      const float4 z = {0.f, 0.f, 0.f, 0.f};
#pragma unroll
      for (int q = 0; q < 8; ++q) *(float4*)&rows[r][off + 4 * q] = z;
    }
  }
  __syncthreads();
  {  // G[j][i] = row_j . row_i  (thread: j = tid>>3, i = (tid&7)*4 .. +3)
    const int j = tid >> 3, i0 = (tid & 7) * 4;
    float a0 = 0, a1 = 0, a2 = 0, a3 = 0;
    for (int e = 0; e < Hz; e += 4) {
      const float4 rj = *(const float4*)&rows[j][e];
      const float4 c0 = *(const float4*)&rows[i0 + 0][e];
      const float4 c1 = *(const float4*)&rows[i0 + 1][e];
      const float4 c2 = *(const float4*)&rows[i0 + 2][e];
      const float4 c3 = *(const float4*)&rows[i0 + 3][e];
      a0 += rj.x * c0.x + rj.y * c0.y + rj.z * c0.z + rj.w * c0.w;
      a1 += rj.x * c1.x + rj.y * c1.y + rj.z * c1.z + rj.w * c1.w;
      a2 += rj.x * c2.x + rj.y * c2.y + rj.z * c2.z + rj.w * c2.w;
      a3 += rj.x * c3.x + rj.y * c3.y + rj.z * c3.z + rj.w * c3.w;
    }
    Gs[j][i0 + 0] = a0; Gs[j][i0 + 1] = a1;
    Gs[j][i0 + 2] = a2; Gs[j][i0 + 3] = a3;
  }
  __syncthreads();
  if (tid < 32) {  // column c of W via forward substitution
    const int c = tid;
    float w[32];
#pragma unroll
    for (int i = 0; i < 32; ++i) w[i] = (i == c) ? 1.0f : 0.0f;
    for (int i = c + 1; i < 32; ++i) {
      float s = 0.0f;
      for (int j = c; j < i; ++j) s = fmaf(Gs[j][i], w[j], s);
      w[i] = -CF * s;
    }
    float* dst = Wt + ((long)(b * NB + bi) << 10) + c * 32;
#pragma unroll
    for (int q = 0; q < 8; ++q)
      *(float4*)(dst + 4 * q) = *(const float4*)&w[4 * q];
  }
}

// ---------------------------------------------------------------------------
// Serial recurrence, u only. One wave per batch, T=32 per block, no LDS,
// no barriers, no in-loop solve (d = Wt p, independent FMAs). Stores d_s.
// ---------------------------------------------------------------------------
__global__ __launch_bounds__(64, 1) void k_recur(
    const float* __restrict__ h, const float* __restrict__ hn,
    const float* __restrict__ Wt, float* __restrict__ d_all)
{
  const int b = blockIdx.x, lane = threadIdx.x;
  const int jl = lane & 31;
  const float* hb  = h  + (long)b * Lz * Hz;
  const float* hnb = hn + (long)b * Lz * Hz;
  const int off = lane << 2;
  float4 u = *(const float4*)(hb + 511 * Hz + off);

  for (int blk = 0; blk < NB; ++blk) {
    const int t0 = 510 - blk * Tb;
    const float* wbase = Wt + ((long)(b * NB + blk) << 10) + jl;
    float wt[32];
#pragma unroll
    for (int k = 0; k < 32; ++k) wt[k] = wbase[k * 32];
    float4 kn[32];
#pragma unroll
    for (int i = 0; i < 32; ++i)
      kn[i] = *(const float4*)(hnb + (long)(t0 - i) * Hz + off);
    if (blk == NB - 1) kn[31] = float4{0.f, 0.f, 0.f, 0.f};  // dummy t=-1

    float p[32];
#pragma unroll
    for (int i = 0; i < 32; ++i)
      p[i] = kn[i].x * u.x + kn[i].y * u.y + kn[i].z * u.z + kn[i].w * u.w;
#pragma unroll
    for (int s = 32; s >= 1; s >>= 1)
#pragma unroll
      for (int i = 0; i < 32; ++i) p[i] += __shfl_xor(p[i], s);

    float dj = 0.0f;
#pragma unroll
    for (int k = 0; k < 32; ++k) dj = fmaf(wt[k], p[k], dj);
    if (lane < 32) d_all[(b << 9) + blk * Tb + jl] = dj;

    float d[32];
#pragma unroll
    for (int k = 0; k < 32; ++k) d[k] = __shfl(dj, k);
#pragma unroll
    for (int i = 0; i < 32; ++i) {
      const float cd = CF * d[i];
      u.x = fmaf(-cd, kn[i].x, u.x); u.y = fmaf(-cd, kn[i].y, u.y);
      u.z = fmaf(-cd, kn[i].z, u.z); u.w = fmaf(-cd, kn[i].w, u.w);
    }
  }
}

// ---------------------------------------------------------------------------
// m[b] = CF * sum_s d_s k_{t_s}  then  r[b] = m @ Wrp + brp.
// One WG (256 thr) per batch; both phases coalesced GEMVs.
// ---------------------------------------------------------------------------
__global__ __launch_bounds__(256) void k_mr(
    const float* __restrict__ h, const float* __restrict__ d_all,
    const float* __restrict__ Wrp, const float* __restrict__ brp,
    float* __restrict__ r)
{
  __shared__ float ms[Hz];
  const int b = blockIdx.x, tid = threadIdx.x;
  const float* hb = h + (long)b * Lz * Hz;
  const float* db = d_all + (b << 9);
  float acc = 0.0f;
#pragma unroll 8
  for (int t = 0; t < 511; ++t)        // s = 510 - t
    acc = fmaf(db[510 - t], hb[(long)t * Hz + tid], acc);
  ms[tid] = CF * acc;
  __syncthreads();
  float racc = 0.0f;
#pragma unroll 8
  for (int e = 0; e < Hz; ++e)
    racc = fmaf(ms[e], Wrp[(long)e * Hz + tid], racc);
  r[b * Hz + tid] = racc + brp[tid];
}

// ---------------------------------------------------------------------------
// out[8,32000] = r[8,256] @ Wout[256,32000] + bout.
// ---------------------------------------------------------------------------
__global__ __launch_bounds__(256) void k_outproj(
    const float* __restrict__ r, const float* __restrict__ Wout,
    const float* __restrict__ bout, float* __restrict__ out)
{
  __shared__ float rs[8 * Hz];
  __shared__ float part[4][8][64];
  const int tid = threadIdx.x, w = tid >> 6, lane = tid & 63;
  ((float4*)rs)[tid * 2 + 0] = ((const float4*)r)[tid * 2 + 0];
  ((float4*)rs)[tid * 2 + 1] = ((const float4*)r)[tid * 2 + 1];
  __syncthreads();
  const int col = blockIdx.x * 64 + lane;
  float acc[8] = {};
  const int i0 = w << 6;
#pragma unroll 8
  for (int ii = 0; ii < 64; ++ii) {
    const int i = i0 + ii;
    const float wv = Wout[(long)i * Vz + col];
#pragma unroll
    for (int bb = 0; bb < 8; ++bb) acc[bb] = fmaf(rs[bb * Hz + i], wv, acc[bb]);
  }
#pragma unroll
  for (int bb = 0; bb < 8; ++bb) part[w][bb][lane] = acc[bb];
  __syncthreads();
  const float bo = bout[col];
  float s0 = part[0][w][lane] + part[1][w][lane] + part[2][w][lane] + part[3][w][lane];
  out[(long)w * Vz + col] = s0 + bo;
  const int w4 = w + 4;
  float s1 = part[0][w4][lane] + part[1][w4][lane] + part[2][w4][lane] + part[3][w4][lane];
  out[(long)w4 * Vz + col] = s1 + bo;
}

// ---------------------------------------------------------------------------
extern "C" void kernel_launch(void* const* d_in, const int* in_sizes, int n_in,
                              void* d_out, int out_size, void* d_ws, size_t ws_size,
                              hipStream_t stream)
{
  const int*   seq   = (const int*)  d_in[0];
  const float* embed = (const float*)d_in[1];
  const float* W1    = (const float*)d_in[2];
  const float* b1    = (const float*)d_in[3];
  const float* W2    = (const float*)d_in[4];
  const float* b2    = (const float*)d_in[5];
  const float* gamma = (const float*)d_in[6];
  const float* beta  = (const float*)d_in[7];
  const float* Wrp   = (const float*)d_in[8];
  const float* brp   = (const float*)d_in[9];
  const float* Wout  = (const float*)d_in[10];
  const float* bout  = (const float*)d_in[11];
  float* out = (float*)d_out;

  char* ws = (char*)d_ws;
  float* y1   = (float*)ws;                                      // 8 MB
  float* xb   = (float*)(ws + 8u  * 1024 * 1024);                // 4 MB
  float* hb   = (float*)(ws + 12u * 1024 * 1024);                // 4 MB
  float* hnb  = (float*)(ws + 16u * 1024 * 1024);                // 4 MB
  float* rb   = (float*)(ws + 20u * 1024 * 1024);                // 8 KB
  float* Wt   = (float*)(ws + 20u * 1024 * 1024 + 16 * 1024);    // 512 KB
  float* dall = (float*)(ws + 20u * 1024 * 1024 + 16 * 1024 + 512 * 1024);  // 16 KB

  k_gemm1<<<dim3(H2z / 64, Mz / 64), 256, 0, stream>>>(seq, embed, W1, b1, y1);
  k_gemm2<<<dim3(Hz / 64, Mz / 64), 256, 0, stream>>>(seq, embed, y1, W2, b2, xb);
  k_ln<<<Mz / 4, 256, 0, stream>>>(xb, gamma, beta, hb, hnb);
  k_gramw<<<dim3(NB, Bz), 256, 0, stream>>>(hnb, Wt);
  k_recur<<<Bz, 64, 0, stream>>>(hb, hnb, Wt, dall);
  k_mr<<<Bz, 256, 0, stream>>>(hb, dall, Wrp, brp, rb);
  k_outproj<<<Vz / 64, 256, 0, stream>>>(rb, Wout, bout, out);
}

// Round 5
// 237.111 us; speedup vs baseline: 1.3199x; 1.2262x over previous
//
#include <hip/hip_runtime.h>

// Problem constants
constexpr int Bz  = 8;
constexpr int Lz  = 512;
constexpr int Hz  = 256;
constexpr int H2z = 512;
constexpr int Vz  = 32000;
constexpr int Mz  = Bz * Lz;      // 4096 tokens
constexpr float CF = 0.05f;       // 1 - ALPHA
constexpr int Tb  = 32;           // recurrence block size
constexpr int NB  = 16;           // blocks: Tb*NB = 512 = 511 real steps + 1 dummy

typedef __attribute__((ext_vector_type(8))) short bfrag8;   // 8 bf16
typedef __attribute__((ext_vector_type(4))) float f32x4v;
typedef __attribute__((ext_vector_type(4))) short s4v;

#define GLOBAL_AS __attribute__((address_space(1)))
#define LDS_AS    __attribute__((address_space(3)))

static __device__ __forceinline__ short f2bf(float f) {
  unsigned u = __builtin_bit_cast(unsigned, f);
  u += 0x7fffu + ((u >> 16) & 1u);           // round-to-nearest-even
  return (short)(u >> 16);
}

// ---------------------------------------------------------------------------
// Gather + convert: Abf[m][k] = bf16(embed[seq[m]][k]).  4 tokens per WG.
// ---------------------------------------------------------------------------
__global__ __launch_bounds__(256) void k_gather(
    const int* __restrict__ seq, const float* __restrict__ embed,
    short* __restrict__ Abf)
{
  const int m = blockIdx.x * 4 + (threadIdx.x >> 6);
  const int lane = threadIdx.x & 63;
  const float4 v = *(const float4*)(embed + (long)seq[m] * Hz + (lane << 2));
  s4v o = { f2bf(v.x), f2bf(v.y), f2bf(v.z), f2bf(v.w) };
  *(s4v*)(Abf + (long)m * Hz + (lane << 2)) = o;
}

// ---------------------------------------------------------------------------
// Transpose + convert weights: dst[n][k] = bf16(src[k][n]).  src is KxN fp32.
// grid: (N/64, K/64), 256 thr.
// ---------------------------------------------------------------------------
__global__ __launch_bounds__(256) void k_wcvt(
    const float* __restrict__ src, short* __restrict__ dst, int K, int N)
{
  __shared__ float tile[64][68];
  const int n0 = blockIdx.x * 64, k0 = blockIdx.y * 64;
  const int tid = threadIdx.x;
  const int rr = tid >> 4, c4 = (tid & 15) << 2;
#pragma unroll
  for (int q = 0; q < 4; ++q) {
    const int kr = rr + q * 16;
    *(float4*)&tile[kr][c4] = *(const float4*)(src + (long)(k0 + kr) * N + n0 + c4);
  }
  __syncthreads();
#pragma unroll
  for (int q = 0; q < 4; ++q) {
    const int nr = rr + q * 16;
    s4v o = { f2bf(tile[c4 + 0][nr]), f2bf(tile[c4 + 1][nr]),
              f2bf(tile[c4 + 2][nr]), f2bf(tile[c4 + 3][nr]) };
    *(s4v*)(dst + (long)(n0 + nr) * K + k0 + c4) = o;
  }
}

// ---------------------------------------------------------------------------
// MFMA GEMM1: y1bf[4096,512] = bf16(relu(Abf @ Wt1^T + b1))
// Abf [M,256] bf16 row-major; Wt1 [512,256] bf16 (= W1^T).  64x64 tile,
// 4 waves, each wave 16(M)x64(N) via 4x mfma_f32_16x16x32_bf16.
// ---------------------------------------------------------------------------
__global__ __launch_bounds__(256) void k_mfma1(
    const short* __restrict__ Abf, const short* __restrict__ Wt1,
    const float* __restrict__ b1, short* __restrict__ y1bf)
{
  __shared__ short As[64][32];
  __shared__ short Bs[64][32];
  const int tid = threadIdx.x;
  const int n0 = blockIdx.x * 64, m0 = blockIdx.y * 64;
  const int w = tid >> 6, l = tid & 63;
  const int srow = tid >> 2, skq = (tid & 3) << 3;
  const f32x4v zero = {0.f, 0.f, 0.f, 0.f};
  f32x4v acc[4] = {zero, zero, zero, zero};
  for (int kc = 0; kc < Hz; kc += 32) {
    __syncthreads();
    *(bfrag8*)&As[srow][skq] = *(const bfrag8*)(Abf + (long)(m0 + srow) * Hz + kc + skq);
    *(bfrag8*)&Bs[srow][skq] = *(const bfrag8*)(Wt1 + (long)(n0 + srow) * Hz + kc + skq);
    __syncthreads();
    const bfrag8 a = *(const bfrag8*)&As[(w << 4) + (l & 15)][(l >> 4) << 3];
#pragma unroll
    for (int nn = 0; nn < 4; ++nn) {
      const bfrag8 bb = *(const bfrag8*)&Bs[(nn << 4) + (l & 15)][(l >> 4) << 3];
      acc[nn] = __builtin_amdgcn_mfma_f32_16x16x32_bf16(a, bb, acc[nn], 0, 0, 0);
    }
  }
  const int col0 = l & 15, quad = l >> 4;
#pragma unroll
  for (int nn = 0; nn < 4; ++nn) {
    const int col = n0 + (nn << 4) + col0;
    const float bias = b1[col];
#pragma unroll
    for (int i = 0; i < 4; ++i) {
      const int row = m0 + (w << 4) + (quad << 2) + i;
      y1bf[(long)row * H2z + col] = f2bf(fmaxf(acc[nn][i] + bias, 0.0f));
    }
  }
}

// ---------------------------------------------------------------------------
// MFMA GEMM2: x[4096,256] = y1bf @ Wt2^T + b2 + embed[seq]  (fp32 out)
// ---------------------------------------------------------------------------
__global__ __launch_bounds__(256) void k_mfma2(
    const int* __restrict__ seq, const float* __restrict__ embed,
    const short* __restrict__ y1bf, const short* __restrict__ Wt2,
    const float* __restrict__ b2, float* __restrict__ x)
{
  __shared__ short As[64][32];
  __shared__ short Bs[64][32];
  const int tid = threadIdx.x;
  const int n0 = blockIdx.x * 64, m0 = blockIdx.y * 64;
  const int w = tid >> 6, l = tid & 63;
  const int srow = tid >> 2, skq = (tid & 3) << 3;
  const f32x4v zero = {0.f, 0.f, 0.f, 0.f};
  f32x4v acc[4] = {zero, zero, zero, zero};
  for (int kc = 0; kc < H2z; kc += 32) {
    __syncthreads();
    *(bfrag8*)&As[srow][skq] = *(const bfrag8*)(y1bf + (long)(m0 + srow) * H2z + kc + skq);
    *(bfrag8*)&Bs[srow][skq] = *(const bfrag8*)(Wt2 + (long)(n0 + srow) * H2z + kc + skq);
    __syncthreads();
    const bfrag8 a = *(const bfrag8*)&As[(w << 4) + (l & 15)][(l >> 4) << 3];
#pragma unroll
    for (int nn = 0; nn < 4; ++nn) {
      const bfrag8 bb = *(const bfrag8*)&Bs[(nn << 4) + (l & 15)][(l >> 4) << 3];
      acc[nn] = __builtin_amdgcn_mfma_f32_16x16x32_bf16(a, bb, acc[nn], 0, 0, 0);
    }
  }
  const int col0 = l & 15, quad = l >> 4;
#pragma unroll
  for (int i = 0; i < 4; ++i) {
    const int row = m0 + (w << 4) + (quad << 2) + i;
    const long ebase = (long)seq[row] * Hz;
#pragma unroll
    for (int nn = 0; nn < 4; ++nn) {
      const int col = n0 + (nn << 4) + col0;
      x[(long)row * Hz + col] = acc[nn][i] + b2[col] + embed[ebase + col];
    }
  }
}

// ---------------------------------------------------------------------------
// LayerNorm + L2-normalized copy. One wave per row, 4 elems/lane.
// ---------------------------------------------------------------------------
__global__ __launch_bounds__(256) void k_ln(
    const float* __restrict__ x, const float* __restrict__ gamma,
    const float* __restrict__ beta, float* __restrict__ h,
    float* __restrict__ hn)
{
  const int lane = threadIdx.x & 63;
  const long row = (long)blockIdx.x * 4 + (threadIdx.x >> 6);
  const int off = lane << 2;
  const float4 xv = *(const float4*)(x + row * Hz + off);
  float s  = xv.x + xv.y + xv.z + xv.w;
  float ss = xv.x * xv.x + xv.y * xv.y + xv.z * xv.z + xv.w * xv.w;
#pragma unroll
  for (int o = 32; o >= 1; o >>= 1) { s += __shfl_xor(s, o); ss += __shfl_xor(ss, o); }
  const float mu   = s * (1.0f / Hz);
  const float var  = ss * (1.0f / Hz) - mu * mu;
  const float rstd = rsqrtf(var + 1e-5f);
  const float4 gv = *(const float4*)(gamma + off);
  const float4 bv = *(const float4*)(beta + off);
  float4 hv;
  hv.x = (xv.x - mu) * rstd * gv.x + bv.x;
  hv.y = (xv.y - mu) * rstd * gv.y + bv.y;
  hv.z = (xv.z - mu) * rstd * gv.z + bv.z;
  hv.w = (xv.w - mu) * rstd * gv.w + bv.w;
  *(float4*)(h + row * Hz + off) = hv;
  float hs = hv.x * hv.x + hv.y * hv.y + hv.z * hv.z + hv.w * hv.w;
#pragma unroll
  for (int o = 32; o >= 1; o >>= 1) hs += __shfl_xor(hs, o);
  const float inv = 1.0f / fmaxf(sqrtf(hs), 1e-12f);
  float4 nv = {hv.x * inv, hv.y * inv, hv.z * inv, hv.w * inv};
  *(float4*)(hn + row * Hz + off) = nv;
}

// ---------------------------------------------------------------------------
// Gram + precomputed block-solve inverse. One WG per (block bi, batch b).
// Solves (I + CF*L) W = I; stores W transposed: Wt[k*32+j] = W[j][k].
// ---------------------------------------------------------------------------
__global__ __launch_bounds__(256) void k_gramw(
    const float* __restrict__ hn, float* __restrict__ Wt)
{
  __shared__ float rows[32][260];
  __shared__ float Gs[32][33];
  const int bi = blockIdx.x, b = blockIdx.y;
  const int tid = threadIdx.x;
  const float* hnb = hn + (long)b * Lz * Hz;
  const int t0 = 510 - bi * Tb;
  {
    const int r = tid >> 3, off = (tid & 7) * 32;
    const int t = t0 - r;
    if (t >= 0) {
      const float* src = hnb + (long)t * Hz + off;
#pragma unroll
      for (int q = 0; q < 8; ++q)
        *(float4*)&rows[r][off + 4 * q] = *(const float4*)(src + 4 * q);
    } else {
      const float4 z = {0.f, 0.f, 0.f, 0.f};
#pragma unroll
      for (int q = 0; q < 8; ++q) *(float4*)&rows[r][off + 4 * q] = z;
    }
  }
  __syncthreads();
  {
    const int j = tid >> 3, i0 = (tid & 7) * 4;
    float a0 = 0, a1 = 0, a2 = 0, a3 = 0;
    for (int e = 0; e < Hz; e += 4) {
      const float4 rj = *(const float4*)&rows[j][e];
      const float4 c0 = *(const float4*)&rows[i0 + 0][e];
      const float4 c1 = *(const float4*)&rows[i0 + 1][e];
      const float4 c2 = *(const float4*)&rows[i0 + 2][e];
      const float4 c3 = *(const float4*)&rows[i0 + 3][e];
      a0 += rj.x * c0.x + rj.y * c0.y + rj.z * c0.z + rj.w * c0.w;
      a1 += rj.x * c1.x + rj.y * c1.y + rj.z * c1.z + rj.w * c1.w;
      a2 += rj.x * c2.x + rj.y * c2.y + rj.z * c2.z + rj.w * c2.w;
      a3 += rj.x * c3.x + rj.y * c3.y + rj.z * c3.z + rj.w * c3.w;
    }
    Gs[j][i0 + 0] = a0; Gs[j][i0 + 1] = a1;
    Gs[j][i0 + 2] = a2; Gs[j][i0 + 3] = a3;
  }
  __syncthreads();
  if (tid < 32) {
    const int c = tid;
    float w[32];
#pragma unroll
    for (int i = 0; i < 32; ++i) w[i] = (i == c) ? 1.0f : 0.0f;
    for (int i = c + 1; i < 32; ++i) {
      float s = 0.0f;
      for (int j = c; j < i; ++j) s = fmaf(Gs[j][i], w[j], s);
      w[i] = -CF * s;
    }
    float* dst = Wt + ((long)(b * NB + bi) << 10) + c * 32;
#pragma unroll
    for (int q = 0; q < 8; ++q)
      *(float4*)(dst + 4 * q) = *(const float4*)&w[4 * q];
  }
}

// ---------------------------------------------------------------------------
// Serial recurrence, u only, LDS double-buffered with async global->LDS
// prefetch (next block's 32 kn rows land while current block computes).
// One wave per batch. Stores d_s for the parallel m-accumulation.
// ---------------------------------------------------------------------------
__global__ __launch_bounds__(64, 1) void k_recur(
    const float* __restrict__ h, const float* __restrict__ hn,
    const float* __restrict__ Wt, float* __restrict__ d_all)
{
  __shared__ __align__(16) float kls[2][32][256];   // 64 KB double buffer
  const int b = blockIdx.x, lane = threadIdx.x;
  const int jl = lane & 31;
  const float* hb  = h  + (long)b * Lz * Hz;
  const float* hnb = hn + (long)b * Lz * Hz;
  const int off = lane << 2;
  float4 u = *(const float4*)(hb + 511 * Hz + off);

  // prefetch block 0 (row i <- t = 510 - i); 16 B/lane covers a full row
#pragma unroll
  for (int i = 0; i < 32; ++i)
    __builtin_amdgcn_global_load_lds(
        (const GLOBAL_AS void*)(hnb + (long)(510 - i) * Hz + off),
        (LDS_AS void*)&kls[0][i][0], 16, 0, 0);

  for (int blk = 0; blk < NB; ++blk) {
    const int cur = blk & 1;
    // wt loads first (so compiler's wait for them keeps prefetch outstanding)
    const float* wbase = Wt + ((long)(b * NB + blk) << 10) + jl;
    float wt[32];
#pragma unroll
    for (int k = 0; k < 32; ++k) wt[k] = wbase[k * 32];

    asm volatile("s_waitcnt vmcnt(0)" ::: "memory");   // buffer `cur` ready
    if (blk + 1 < NB) {
      const int t0n = 510 - (blk + 1) * Tb;
#pragma unroll
      for (int i = 0; i < 32; ++i)
        __builtin_amdgcn_global_load_lds(
            (const GLOBAL_AS void*)(hnb + (long)(t0n - i) * Hz + off),
            (LDS_AS void*)&kls[cur ^ 1][i][0], 16, 0, 0);
    }

    // p = Kn_blk . u (partial dots from LDS, batched 64-lane allreduce)
    float p[32];
#pragma unroll
    for (int i = 0; i < 32; ++i) {
      const float4 kn = *(const float4*)&kls[cur][i][off];
      p[i] = kn.x * u.x + kn.y * u.y + kn.z * u.z + kn.w * u.w;
    }
    if (blk == NB - 1) p[31] = 0.0f;     // dummy t=-1 step
#pragma unroll
    for (int s = 32; s >= 1; s >>= 1)
#pragma unroll
      for (int i = 0; i < 32; ++i) p[i] += __shfl_xor(p[i], s);

    // d = W p (precomputed inverse; independent FMAs, no serial chain)
    float dj = 0.0f;
#pragma unroll
    for (int k = 0; k < 32; ++k) dj = fmaf(wt[k], p[k], dj);
    if (lane < 32) d_all[(b << 9) + blk * Tb + jl] = dj;

    float d[32];
#pragma unroll
    for (int k = 0; k < 32; ++k) d[k] = __shfl(dj, k);

    // u -= CF * Kn_blk^T d (re-read kn from LDS)
#pragma unroll
    for (int i = 0; i < 32; ++i) {
      const float4 kn = *(const float4*)&kls[cur][i][off];
      const float cd = CF * d[i];
      u.x = fmaf(-cd, kn.x, u.x); u.y = fmaf(-cd, kn.y, u.y);
      u.z = fmaf(-cd, kn.z, u.z); u.w = fmaf(-cd, kn.w, u.w);
    }
  }
}

// ---------------------------------------------------------------------------
// m partials: part[b][c][:] = sum_{t in chunk c} d_{510-t} * h[b][t][:]
// grid (32, 8) — fully parallel.
// ---------------------------------------------------------------------------
__global__ __launch_bounds__(256) void k_mrp(
    const float* __restrict__ h, const float* __restrict__ d_all,
    float* __restrict__ part)
{
  const int c = blockIdx.x, b = blockIdx.y, tid = threadIdx.x;
  const float* hb = h + (long)b * Lz * Hz;
  const float* db = d_all + (b << 9);
  const int t0 = c * 16;
  const int t1 = (t0 + 16 < 511) ? t0 + 16 : 511;
  float acc = 0.0f;
#pragma unroll 4
  for (int t = t0; t < t1; ++t)
    acc = fmaf(db[510 - t], hb[(long)t * Hz + tid], acc);
  part[((long)b * 32 + c) * Hz + tid] = acc;
}

// ---------------------------------------------------------------------------
// Combine partials -> m; then r = m @ Wrp + brp.  grid 8.
// ---------------------------------------------------------------------------
__global__ __launch_bounds__(256) void k_mr2(
    const float* __restrict__ part, const float* __restrict__ Wrp,
    const float* __restrict__ brp, float* __restrict__ r)
{
  __shared__ float ms[Hz];
  const int b = blockIdx.x, tid = threadIdx.x;
  float acc = 0.0f;
#pragma unroll
  for (int c = 0; c < 32; ++c) acc += part[((long)b * 32 + c) * Hz + tid];
  ms[tid] = CF * acc;
  __syncthreads();
  float racc = 0.0f;
#pragma unroll 8
  for (int e = 0; e < Hz; ++e)
    racc = fmaf(ms[e], Wrp[(long)e * Hz + tid], racc);
  r[b * Hz + tid] = racc + brp[tid];
}

// ---------------------------------------------------------------------------
// out[8,32000] = r[8,256] @ Wout[256,32000] + bout.
// ---------------------------------------------------------------------------
__global__ __launch_bounds__(256) void k_outproj(
    const float* __restrict__ r, const float* __restrict__ Wout,
    const float* __restrict__ bout, float* __restrict__ out)
{
  __shared__ float rs[8 * Hz];
  __shared__ float part[4][8][64];
  const int tid = threadIdx.x, w = tid >> 6, lane = tid & 63;
  ((float4*)rs)[tid * 2 + 0] = ((const float4*)r)[tid * 2 + 0];
  ((float4*)rs)[tid * 2 + 1] = ((const float4*)r)[tid * 2 + 1];
  __syncthreads();
  const int col = blockIdx.x * 64 + lane;
  float acc[8] = {};
  const int i0 = w << 6;
#pragma unroll 8
  for (int ii = 0; ii < 64; ++ii) {
    const int i = i0 + ii;
    const float wv = Wout[(long)i * Vz + col];
#pragma unroll
    for (int bb = 0; bb < 8; ++bb) acc[bb] = fmaf(rs[bb * Hz + i], wv, acc[bb]);
  }
#pragma unroll
  for (int bb = 0; bb < 8; ++bb) part[w][bb][lane] = acc[bb];
  __syncthreads();
  const float bo = bout[col];
  float s0 = part[0][w][lane] + part[1][w][lane] + part[2][w][lane] + part[3][w][lane];
  out[(long)w * Vz + col] = s0 + bo;
  const int w4 = w + 4;
  float s1 = part[0][w4][lane] + part[1][w4][lane] + part[2][w4][lane] + part[3][w4][lane];
  out[(long)w4 * Vz + col] = s1 + bo;
}

// ---------------------------------------------------------------------------
extern "C" void kernel_launch(void* const* d_in, const int* in_sizes, int n_in,
                              void* d_out, int out_size, void* d_ws, size_t ws_size,
                              hipStream_t stream)
{
  const int*   seq   = (const int*)  d_in[0];
  const float* embed = (const float*)d_in[1];
  const float* W1    = (const float*)d_in[2];
  const float* b1    = (const float*)d_in[3];
  const float* W2    = (const float*)d_in[4];
  const float* b2    = (const float*)d_in[5];
  const float* gamma = (const float*)d_in[6];
  const float* beta  = (const float*)d_in[7];
  const float* Wrp   = (const float*)d_in[8];
  const float* brp   = (const float*)d_in[9];
  const float* Wout  = (const float*)d_in[10];
  const float* bout  = (const float*)d_in[11];
  float* out = (float*)d_out;

  char* ws = (char*)d_ws;
  const size_t MB = 1024u * 1024u;
  short* Abf  = (short*)(ws);                    // 2 MB  [4096,256] bf16
  short* y1bf = (short*)(ws + 2 * MB);           // 4 MB  [4096,512] bf16
  float* xb   = (float*)(ws + 6 * MB);           // 4 MB
  float* hb   = (float*)(ws + 10 * MB);          // 4 MB
  float* hnb  = (float*)(ws + 14 * MB);          // 4 MB
  short* Wt1  = (short*)(ws + 18 * MB);          // 256 KB [512,256] bf16 (W1^T)
  short* Wt2  = (short*)(ws + 18 * MB + 256 * 1024);   // 256 KB [256,512] bf16
  float* Wsol = (float*)(ws + 18 * MB + 512 * 1024);   // 512 KB
  float* dall = (float*)(ws + 19 * MB);                // 16 KB
  float* prt  = (float*)(ws + 19 * MB + 16 * 1024);    // 256 KB
  float* rb   = (float*)(ws + 19 * MB + 288 * 1024);   // 8 KB

  k_gather<<<Mz / 4, 256, 0, stream>>>(seq, embed, Abf);
  k_wcvt<<<dim3(H2z / 64, Hz / 64), 256, 0, stream>>>(W1, Wt1, Hz, H2z);
  k_wcvt<<<dim3(Hz / 64, H2z / 64), 256, 0, stream>>>(W2, Wt2, H2z, Hz);
  k_mfma1<<<dim3(H2z / 64, Mz / 64), 256, 0, stream>>>(Abf, Wt1, b1, y1bf);
  k_mfma2<<<dim3(Hz / 64, Mz / 64), 256, 0, stream>>>(seq, embed, y1bf, Wt2, b2, xb);
  k_ln<<<Mz / 4, 256, 0, stream>>>(xb, gamma, beta, hb, hnb);
  k_gramw<<<dim3(NB, Bz), 256, 0, stream>>>(hnb, Wsol);
  k_recur<<<Bz, 64, 0, stream>>>(hb, hnb, Wsol, dall);
  k_mrp<<<dim3(32, Bz), 256, 0, stream>>>(hb, dall, prt);
  k_mr2<<<Bz, 256, 0, stream>>>(prt, Wrp, brp, rb);
  k_outproj<<<Vz / 64, 256, 0, stream>>>(rb, Wout, bout, out);
}